// Round 8
// baseline (101.652 us; speedup 1.0000x reference)
//
#include <hip/hip_runtime.h>

// LIF neuron scan: x [64, 1024, 512] f32 -> spikes [64, 1024, 512] f32 (0/1)
// m = 0.95*m + x[t]; s = (m > 0.5); m = s ? 0 : m
//
// All single-pass structures pin at ~4.2 TB/s because only 512 waves (2/CU)
// do useful work (32768 sequential chains). This version parallelizes over
// TIME, bit-exactly, using the reset-merge property:
//   Pass 1: 4 time-blocks of 256 steps computed in parallel (2048 waves,
//     8/CU) with guessed m_in = 0 (exact for block 0). Stores each block's
//     m_out to ws. Spikes written for all blocks (exact for block 0,
//     provisional for blocks 1..3).
//   Pass 2: per chain, walk the 3 block junctions: recompute from the TRUE
//     m_in until a step where BOTH the recompute and the pass-1 run fire.
//     At that step both states are exactly 0.0f -> bit-identical onward, so
//     pass-1's remaining spikes and its ws m_out are exact; stop. If no
//     merge by block end, the full recompute (also exact) carries m forward.
// Identical __fmul_rn/__fadd_rn chains in both passes -> bit-exact vs the
// sequential reference (the 0/1 threshold makes any ulp drift avalanche, so
// no reordering of the per-step arithmetic anywhere).

#define BATCH 64
#define SEQ   1024
#define FEAT  512
#define CHUNK 64
#define NTB   4
#define TBL   (SEQ / NTB)          // 256 steps per time-block
#define NCHAIN (BATCH * FEAT)      // 32768 chains
#define PCHUNK 32                  // pass-2 lookahead chunk

#define LOAD_CHUNK(buf, t0)                                              \
    {                                                                    \
        const float* __restrict__ xn = xp + (size_t)(t0) * FEAT;         \
        _Pragma("unroll")                                                \
        for (int u = 0; u < CHUNK; ++u) buf[u] = xn[(size_t)u * FEAT];   \
    }

#define COMPUTE_CHUNK(buf, t0)                                           \
    {                                                                    \
        float* __restrict__ on = op + (size_t)(t0) * FEAT;               \
        _Pragma("unroll")                                                \
        for (int u = 0; u < CHUNK; ++u) {                                \
            m = __fadd_rn(__fmul_rn(0.95f, m), buf[u]);                  \
            const bool fired = (m > 0.5f);                               \
            __builtin_nontemporal_store(fired ? 1.0f : 0.0f,             \
                                        &on[(size_t)u * FEAT]);          \
            m = fired ? 0.0f : m;                                        \
        }                                                                \
    }

// ---- pass 1: parallel over (chain-block, time-block), m_in = 0 guess ----
__global__ __launch_bounds__(64, 1)
void lif_pass1(const float* __restrict__ x, float* __restrict__ out,
               float* __restrict__ ws) {
    const int bid  = blockIdx.x;
    const int lane = threadIdx.x;
    const int cb = bid & 511;          // chain block (512)
    const int tb = bid >> 9;           // time block  (4)
    const int b  = cb >> 3;
    const int f0 = (cb & 7) << 6;
    const size_t base = (size_t)b * SEQ * FEAT + f0 + lane
                      + (size_t)tb * TBL * FEAT;
    const float* __restrict__ xp = x + base;
    float* __restrict__ op = out + base;

    float m = 0.0f;
    float bufA[CHUNK], bufB[CHUNK];
    LOAD_CHUNK(bufA, 0)
    for (int t0 = 0; t0 < TBL; t0 += 2 * CHUNK) {   // 2 iterations
        LOAD_CHUNK(bufB, t0 + CHUNK)
        COMPUTE_CHUNK(bufA, t0)
        if (t0 + 2 * CHUNK < TBL) LOAD_CHUNK(bufA, t0 + 2 * CHUNK)
        COMPUTE_CHUNK(bufB, t0 + CHUNK)
    }
    if (tb < NTB - 1) ws[tb * NCHAIN + (cb << 6) + lane] = m;
}

// ---- pass 2: sequential junction fix-up, stops at first simultaneous fire --
__global__ __launch_bounds__(64, 1)
void lif_pass2(const float* __restrict__ x, float* __restrict__ out,
               const float* __restrict__ ws) {
    const int cb   = blockIdx.x;
    const int lane = threadIdx.x;
    const int b  = cb >> 3;
    const int f0 = (cb & 7) << 6;
    const size_t base = (size_t)b * SEQ * FEAT + f0 + lane;
    const float* __restrict__ xp = x + base;
    float* __restrict__ op = out + base;
    const int idx = (cb << 6) + lane;

    float m = ws[idx];                 // exact m_out of time-block 0
    for (int tb = 1; tb < NTB; ++tb) {
        const int tbase = tb * TBL;
        bool done = false;
        for (int c0 = 0; c0 < TBL; c0 += PCHUNK) {
            if (__all(done)) break;
            float xb[PCHUNK], sb[PCHUNK];
            // lookahead loads (all lanes, keeps the loop wave-uniform;
            // latency amortized over PCHUNK register steps)
#pragma unroll
            for (int u = 0; u < PCHUNK; ++u) {
                xb[u] = xp[(size_t)(tbase + c0 + u) * FEAT];
                sb[u] = op[(size_t)(tbase + c0 + u) * FEAT];
            }
#pragma unroll
            for (int u = 0; u < PCHUNK; ++u) {
                if (!done) {
                    m = __fadd_rn(__fmul_rn(0.95f, m), xb[u]);
                    const bool fired = (m > 0.5f);
                    op[(size_t)(tbase + c0 + u) * FEAT] = fired ? 1.0f : 0.0f;
                    const bool p1 = (sb[u] != 0.0f);   // pass-1 spike
                    if (fired) m = 0.0f;
                    if (fired && p1) done = true;      // states both 0 -> merged
                }
            }
        }
        if (done && tb < NTB - 1) m = ws[tb * NCHAIN + idx];  // pass-1 m_out exact
        // if !done: m is the fully-recomputed (exact) carry
    }
}

// ---- fallback: single-kernel round-3 structure (if ws too small) ----
__global__ __launch_bounds__(64, 1)
void lif_fallback(const float* __restrict__ x, float* __restrict__ out) {
    const int tid = blockIdx.x * 64 + threadIdx.x;
    const int b = tid >> 9;
    const int f = tid & (FEAT - 1);
    const size_t base = (size_t)b * SEQ * FEAT + f;
    const float* __restrict__ xp = x + base;
    float* __restrict__ op = out + base;
    float m = 0.0f;
    float bufA[CHUNK], bufB[CHUNK];
    LOAD_CHUNK(bufA, 0)
    for (int t0 = 0; t0 < SEQ; t0 += 2 * CHUNK) {
        LOAD_CHUNK(bufB, t0 + CHUNK)
        COMPUTE_CHUNK(bufA, t0)
        if (t0 + 2 * CHUNK < SEQ) LOAD_CHUNK(bufA, t0 + 2 * CHUNK)
        COMPUTE_CHUNK(bufB, t0 + CHUNK)
    }
}

extern "C" void kernel_launch(void* const* d_in, const int* in_sizes, int n_in,
                              void* d_out, int out_size, void* d_ws, size_t ws_size,
                              hipStream_t stream) {
    const float* x = (const float*)d_in[0];
    float* out = (float*)d_out;
    const size_t ws_needed = (size_t)(NTB - 1) * NCHAIN * sizeof(float); // 384 KB
    if (ws_size >= ws_needed) {
        lif_pass1<<<NTB * 512, 64, 0, stream>>>(x, out, (float*)d_ws);
        lif_pass2<<<512, 64, 0, stream>>>(x, out, (const float*)d_ws);
    } else {
        lif_fallback<<<512, 64, 0, stream>>>(x, out);
    }
}

// Round 9
// 49.487 us; speedup vs baseline: 2.0541x; 2.0541x over previous
//
#include <hip/hip_runtime.h>

// LIF neuron scan: x [64, 1024, 512] f32 -> spikes [64, 1024, 512] f32 (0/1)
// m = 0.95*m + x[t]; s = (m > 0.5); m = s ? 0 : m
//
// Cross-round evidence (R3 46.9us, R6 prefetchers -36%, R8 time-split pass1
// no faster despite 4x waves): the ceiling is DRAM row-activate locality,
// not MLP. Each 64-lane wave reads 256B per step at 2KB stride -> one row
// activate per 256B. Fix concurrency SHAPE, not amount:
//   - 256-thread blocks (4 waves) own a contiguous 1KB half-row; the four
//     waves' concurrent requests tile 1KB densely instead of 256B islands.
//   - __syncthreads() at each 32-step chunk boundary keeps the block's
//     waves inside one chunk window, so their row accesses coincide.
//   - total waves unchanged (512), chains/lane unchanged (1), per-thread
//     load/compute code identical to the 46.9us round-3 structure.
// Non-fused mul/add (np ref rounds mul and add separately; the 0/1
// threshold makes ulp differences avalanche down the chain) -> absmax 0.

#define BATCH 64
#define SEQ   1024
#define FEAT  512
#define CHUNK 32

#define LOAD_CHUNK(buf, t0)                                              \
    {                                                                    \
        const float* __restrict__ xn = xp + (size_t)(t0) * FEAT;         \
        _Pragma("unroll")                                                \
        for (int u = 0; u < CHUNK; ++u) buf[u] = xn[(size_t)u * FEAT];   \
    }

#define COMPUTE_CHUNK(buf, t0)                                           \
    {                                                                    \
        float* __restrict__ on = op + (size_t)(t0) * FEAT;               \
        _Pragma("unroll")                                                \
        for (int u = 0; u < CHUNK; ++u) {                                \
            m = __fadd_rn(__fmul_rn(0.95f, m), buf[u]);                  \
            const bool fired = (m > 0.5f);                               \
            __builtin_nontemporal_store(fired ? 1.0f : 0.0f,             \
                                        &on[(size_t)u * FEAT]);          \
            m = fired ? 0.0f : m;                                        \
        }                                                                \
    }

__global__ __launch_bounds__(256, 1)
void lif_kernel(const float* __restrict__ x, float* __restrict__ out) {
    const int bid = blockIdx.x;              // 0..127
    const int tid = threadIdx.x;             // 0..255
    const int b   = bid >> 1;                // batch row
    const int f   = ((bid & 1) << 8) + tid;  // contiguous 1KB half-row
    const size_t base = (size_t)b * SEQ * FEAT + f;
    const float* __restrict__ xp = x + base;
    float* __restrict__ op = out + base;

    float m = 0.0f;
    float bufA[CHUNK], bufB[CHUNK];

    LOAD_CHUNK(bufA, 0)

    // 1024 / (2*32) = 16 iterations; barriers keep the 4 waves' request
    // windows overlapped so the block's 1KB row-span stays dense in the
    // DRAM scheduler queue.
    for (int t0 = 0; t0 < SEQ; t0 += 2 * CHUNK) {
        __syncthreads();
        LOAD_CHUNK(bufB, t0 + CHUNK)          // prefetch while computing A
        COMPUTE_CHUNK(bufA, t0)
        __syncthreads();
        if (t0 + 2 * CHUNK < SEQ) {
            LOAD_CHUNK(bufA, t0 + 2 * CHUNK)  // prefetch while computing B
        }
        COMPUTE_CHUNK(bufB, t0 + CHUNK)
    }
}

extern "C" void kernel_launch(void* const* d_in, const int* in_sizes, int n_in,
                              void* d_out, int out_size, void* d_ws, size_t ws_size,
                              hipStream_t stream) {
    const float* x = (const float*)d_in[0];
    float* out = (float*)d_out;
    const int grid = BATCH * 2;              // 128 blocks x 256 threads = 512 waves
    lif_kernel<<<grid, 256, 0, stream>>>(x, out);
}

// Round 10
// 45.422 us; speedup vs baseline: 2.2379x; 1.0895x over previous
//
#include <hip/hip_runtime.h>

// LIF neuron scan: x [64, 1024, 512] f32 -> spikes [64, 1024, 512] f32 (0/1)
// m = 0.95*m + x[t]; s = (m > 0.5); m = s ? 0 : m
// Sequential over t, parallel over (b, f) = 32768 chains (512 waves, 2/CU).
//
// FINAL (best of 9 rounds, 46.9us): register ping-pong double buffer,
// CHUNK=64, ~40-64 outstanding dword loads/wave. Demand traffic 268 MB
// at 5.7 TB/s = 91% of the measured 6.29 TB/s copy ceiling.
// Falsified alternatives: LDS-staged dwordx4 + counted vmcnt (49.4us),
// decoupled prefetch waves (63.8us), system-scope nt stores (53.1us),
// bit-exact time-parallel decomposition (101.7us), 4-wave dense-window
// blocks (49.5us). The remaining ~9% vs pure copy is structural: 32768
// sequential chains cap parallelism at 512 waves with 256B/wave/step
// access granularity, vs copy's unbounded waves and 1KB/wave accesses.
//
// Non-fused mul/add (np ref rounds mul and add separately; the 0/1
// threshold makes ulp differences avalanche down the chain) -> absmax 0.

#define BATCH 64
#define SEQ   1024
#define FEAT  512
#define CHUNK 64

#define LOAD_CHUNK(buf, t0)                                              \
    {                                                                    \
        const float* __restrict__ xn = xp + (size_t)(t0) * FEAT;         \
        _Pragma("unroll")                                                \
        for (int u = 0; u < CHUNK; ++u) buf[u] = xn[(size_t)u * FEAT];   \
    }

#define COMPUTE_CHUNK(buf, t0)                                           \
    {                                                                    \
        float* __restrict__ on = op + (size_t)(t0) * FEAT;               \
        _Pragma("unroll")                                                \
        for (int u = 0; u < CHUNK; ++u) {                                \
            m = __fadd_rn(__fmul_rn(0.95f, m), buf[u]);                  \
            const bool fired = (m > 0.5f);                               \
            __builtin_nontemporal_store(fired ? 1.0f : 0.0f,             \
                                        &on[(size_t)u * FEAT]);          \
            m = fired ? 0.0f : m;                                        \
        }                                                                \
    }

__global__ __launch_bounds__(64, 1)
void lif_kernel(const float* __restrict__ x, float* __restrict__ out) {
    const int tid = blockIdx.x * blockDim.x + threadIdx.x;   // 0..32767
    const int b = tid >> 9;        // / FEAT
    const int f = tid & (FEAT - 1);
    const size_t base = (size_t)b * SEQ * FEAT + f;
    const float* __restrict__ xp = x + base;
    float* __restrict__ op = out + base;

    float m = 0.0f;
    float bufA[CHUNK], bufB[CHUNK];

    LOAD_CHUNK(bufA, 0)

    // 1024 / (2*64) = 8 iterations; static ping-pong, no register-copy join
    for (int t0 = 0; t0 < SEQ; t0 += 2 * CHUNK) {
        LOAD_CHUNK(bufB, t0 + CHUNK)          // prefetch while computing A
        COMPUTE_CHUNK(bufA, t0)
        if (t0 + 2 * CHUNK < SEQ) {
            LOAD_CHUNK(bufA, t0 + 2 * CHUNK)  // prefetch while computing B
        }
        COMPUTE_CHUNK(bufB, t0 + CHUNK)
    }
}

extern "C" void kernel_launch(void* const* d_in, const int* in_sizes, int n_in,
                              void* d_out, int out_size, void* d_ws, size_t ws_size,
                              hipStream_t stream) {
    const float* x = (const float*)d_in[0];
    float* out = (float*)d_out;
    const int total_threads = BATCH * FEAT;      // 32768
    const int block = 64;
    const int grid = total_threads / block;      // 512 blocks -> 2 waves/CU
    lif_kernel<<<grid, block, 0, stream>>>(x, out);
}